// Round 8
// baseline (188.060 us; speedup 1.0000x reference)
//
#include <hip/hip_runtime.h>

typedef float f32x4 __attribute__((ext_vector_type(4)));
typedef __bf16 bf16x8 __attribute__((ext_vector_type(8)));
typedef __bf16 bf16x4 __attribute__((ext_vector_type(4)));

constexpr float INV_SQRT_F = 0.17677669529663687f;  // 32^-0.5

__device__ __forceinline__ f32x4 mfma16(bf16x8 a, bf16x8 b) {
  const f32x4 z = {0.f, 0.f, 0.f, 0.f};
  return __builtin_amdgcn_mfma_f32_16x16x32_bf16(a, b, z, 0, 0, 0);
}

__device__ __forceinline__ f32x4 ld4(const float* __restrict__ p) {
  return *reinterpret_cast<const f32x4*>(p);
}
__device__ __forceinline__ bf16x8 ldb8(const __bf16* __restrict__ p) {
  return *reinterpret_cast<const bf16x8*>(p);
}

// ---------------- pre-pass: h -> bf16, W -> scaled WFRAG-layout bf16 -------
// ws layout (bytes): [0, 24576) W frags (1536 x bf16x8);
//                    [24576, ...) hb0 | hb1 | hb2 (bf16, same elem order as h)
__global__ __launch_bounds__(256)
void leibniz_prepass(const float* __restrict__ h0, const float* __restrict__ h1,
                     const float* __restrict__ h2, const float* __restrict__ Wg,
                     __bf16* __restrict__ ws, int n0, int n1, int n2)
{
  // W fragments (block 0 only): entry c=(p,hf,qq,gl) -> W[p][hf*16+gl][qq*8+j]
  if (blockIdx.x == 0) {
    bf16x8* wsW = reinterpret_cast<bf16x8*>(ws);
    for (int c = threadIdx.x; c < 12 * 2 * 4 * 16; c += 256) {
      const int gl = c & 15;
      const int qq = (c >> 4) & 3;
      const int hf = (c >> 6) & 1;
      const int p  = c >> 7;
      const float* wp = Wg + (p * 32 + hf * 16 + gl) * 32 + qq * 8;
      bf16x8 f;
#pragma unroll
      for (int j = 0; j < 8; ++j) f[j] = (__bf16)(wp[j] * INV_SQRT_F);
      wsW[c] = f;
    }
  }
  // h conversion, grid-stride over f32x4 quads
  __bf16* hb0 = ws + 12288;
  __bf16* hb1 = hb0 + n0;
  __bf16* hb2 = hb1 + n1;
  const int q0 = n0 >> 2, q1 = n1 >> 2, q2 = n2 >> 2;
  const int total = q0 + q1 + q2;
  for (int i = blockIdx.x * 256 + threadIdx.x; i < total; i += gridDim.x * 256) {
    const float* sp;
    __bf16* dp;
    if (i < q0)            { sp = h0 + 4 * i;              dp = hb0 + 4 * i; }
    else if (i < q0 + q1)  { int j = i - q0;      sp = h1 + 4 * j; dp = hb1 + 4 * j; }
    else                   { int j = i - q0 - q1; sp = h2 + 4 * j; dp = hb2 + 4 * j; }
    const f32x4 v = *reinterpret_cast<const f32x4*>(sp);
    bf16x4 o;
    o[0] = (__bf16)v[0]; o[1] = (__bf16)v[1]; o[2] = (__bf16)v[2]; o[3] = (__bf16)v[3];
    *reinterpret_cast<bf16x4*>(dp) = o;
  }
}

// ---------------- main kernel (R4/R5 structure, bf16 direct gather) --------
// One wave = 16 edges, both feature halves. Lane owns a contiguous feature
// float4 per (edge, spatial) row. h gathered as 13 bf16x8 loads landing
// DIRECTLY in MFMA fragment registers (no f32 staging, no cvt chain — R7's
// batched issue without R7's spill).
__global__ __launch_bounds__(256, 2)
void leibniz_fused_b(const __bf16* __restrict__ wsAll,
                     const float* __restrict__ g0, const float* __restrict__ g1,
                     const float* __restrict__ g2, const int* __restrict__ src,
                     float* __restrict__ out, int E, int n0, int n1)
{
  __shared__ bf16x8 wlds[12 * 2 * 4 * 16];
  {
    const bf16x8* wsW = reinterpret_cast<const bf16x8*>(wsAll);
    for (int c = threadIdx.x; c < 12 * 2 * 4 * 16; c += 256) wlds[c] = wsW[c];
  }
  __syncthreads();

  const __bf16* hb0 = wsAll + 12288;
  const __bf16* hb1 = hb0 + n0;
  const __bf16* hb2 = hb1 + n1;

  const int lane = threadIdx.x & 63;
  const int wid  = threadIdx.x >> 6;
  const int eidx = lane & 15;
  const int q    = lane >> 4;
  int e0 = (blockIdx.x * 4 + wid) * 16;
  if (e0 > E - 16) e0 = E - 16;

  const int node = src[e0 + eidx];
  const int k0 = q * 8;

  const int e   = e0 + eidx;
  const int col = q * 4;
  const float* g0p = g0 + e * 32 + col;
  const float* g1p = g1 + (long long)e * 96 + col;
  const float* g2p = g2 + (long long)e * 288 + col;

  // ---- issue g0 + g1 first (HBM, longest latency)
  f32x4 gv0[2];
  gv0[0] = ld4(g0p);
  gv0[1] = ld4(g0p + 16);
  f32x4 gv1[3][2];
#pragma unroll
  for (int s = 0; s < 3; ++s) {
    gv1[s][0] = ld4(g1p + s * 32);
    gv1[s][1] = ld4(g1p + s * 32 + 16);
  }

  // ---- h gather: 13 x 16B bf16 loads straight into fragment registers
  const bf16x8 b0 = ldb8(hb0 + node * 32 + k0);
  bf16x8 b1[3];
#pragma unroll
  for (int s = 0; s < 3; ++s) b1[s] = ldb8(hb1 + node * 96 + s * 32 + k0);
  bf16x8 b2[9];
#pragma unroll
  for (int s = 0; s < 9; ++s) b2[s] = ldb8(hb2 + (long long)node * 288 + s * 32 + k0);

  // ---- issue g2 rows 0 and 1 (rolling 2-buffer pipeline)
  f32x4 gkA[3][2], gkB[3][2];
#pragma unroll
  for (int j = 0; j < 3; ++j) {
    gkA[j][0] = ld4(g2p + j * 32);
    gkA[j][1] = ld4(g2p + j * 32 + 16);
  }
#pragma unroll
  for (int j = 0; j < 3; ++j) {
    gkB[j][0] = ld4(g2p + (3 + j) * 32);
    gkB[j][1] = ld4(g2p + (3 + j) * 32 + 16);
  }

  const f32x4 z4 = {0.f, 0.f, 0.f, 0.f};
  f32x4 acc0[2] = {z4, z4};
  f32x4 acc1[3][2];
  f32x4 acc2[9][2];
#pragma unroll
  for (int s = 0; s < 3; ++s) { acc1[s][0] = z4; acc1[s][1] = z4; }
#pragma unroll
  for (int s = 0; s < 9; ++s) { acc2[s][0] = z4; acc2[s][1] = z4; }

#define WFRAG(P, H) (wlds[(((P) * 2 + (H)) * 4 + q) * 16 + eidx])

  // ---- g0 phase: paths 0, 3, 4 (prod)
#pragma unroll
  for (int h = 0; h < 2; ++h) {
    acc0[h] += mfma16(WFRAG(0, h), b0) * gv0[h];
    const bf16x8 w3 = WFRAG(3, h);
#pragma unroll
    for (int s = 0; s < 3; ++s) acc1[s][h] += mfma16(w3, b1[s]) * gv0[h];
    const bf16x8 w4 = WFRAG(4, h);
#pragma unroll
    for (int s = 0; s < 9; ++s) acc2[s][h] += mfma16(w4, b2[s]) * gv0[h];
  }

  // ---- g1 phase: paths 1 (prod), 5 (dot), 6 (cross), 7 (outer), 8 (mat_vec)
#pragma unroll
  for (int h = 0; h < 2; ++h) {
    {
      const f32x4 t = mfma16(WFRAG(1, h), b0);
#pragma unroll
      for (int s = 0; s < 3; ++s) acc1[s][h] += t * gv1[s][h];
    }
    {
      const bf16x8 w5 = WFRAG(5, h);
#pragma unroll
      for (int s = 0; s < 3; ++s) acc0[h] += mfma16(w5, b1[s]) * gv1[s][h];
    }
    {
      const bf16x8 w6 = WFRAG(6, h);
      const f32x4 c0 = mfma16(w6, b1[0]);
      const f32x4 c1 = mfma16(w6, b1[1]);
      const f32x4 c2 = mfma16(w6, b1[2]);
      acc1[0][h] += c1 * gv1[2][h] - c2 * gv1[1][h];
      acc1[1][h] += c2 * gv1[0][h] - c0 * gv1[2][h];
      acc1[2][h] += c0 * gv1[1][h] - c1 * gv1[0][h];
    }
    {
      const bf16x8 w7 = WFRAG(7, h);
      const f32x4 o0 = mfma16(w7, b1[0]);
      const f32x4 o1 = mfma16(w7, b1[1]);
      const f32x4 o2 = mfma16(w7, b1[2]);
      const f32x4 tr3 = (o0 * gv1[0][h] + o1 * gv1[1][h] + o2 * gv1[2][h]) * (1.f / 3.f);
      acc2[0][h] += o0 * gv1[0][h] - tr3;
      acc2[1][h] += o0 * gv1[1][h];
      acc2[2][h] += o0 * gv1[2][h];
      acc2[3][h] += o1 * gv1[0][h];
      acc2[4][h] += o1 * gv1[1][h] - tr3;
      acc2[5][h] += o1 * gv1[2][h];
      acc2[6][h] += o2 * gv1[0][h];
      acc2[7][h] += o2 * gv1[1][h];
      acc2[8][h] += o2 * gv1[2][h] - tr3;
    }
    {
      const bf16x8 w8 = WFRAG(8, h);
#pragma unroll
      for (int i = 0; i < 3; ++i)
#pragma unroll
        for (int j = 0; j < 3; ++j)
          acc1[i][h] += mfma16(w8, b2[i * 3 + j]) * gv1[j][h];
    }
  }

  // ---- g2 phase: paths 2 (prod), 9 (vec_mat), 10 (double_dot), 11 (mat_mul_sym)
  f32x4 t2[2];
  t2[0] = mfma16(WFRAG(2, 0), b0);
  t2[1] = mfma16(WFRAG(2, 1), b0);

#define G2ROW_COMPUTE(K, GK)                                                   \
  {                                                                            \
    _Pragma("unroll")                                                          \
    for (int h = 0; h < 2; ++h) {                                              \
      _Pragma("unroll")                                                        \
      for (int j = 0; j < 3; ++j) acc2[(K) * 3 + j][h] += t2[h] * GK[j][h];    \
      {                                                                        \
        const f32x4 vk = mfma16(WFRAG(9, h), b1[(K)]);                         \
        _Pragma("unroll")                                                      \
        for (int j = 0; j < 3; ++j) acc1[j][h] += vk * GK[j][h];               \
      }                                                                        \
      {                                                                        \
        const bf16x8 w10 = WFRAG(10, h);                                       \
        _Pragma("unroll")                                                      \
        for (int j = 0; j < 3; ++j)                                            \
          acc0[h] += mfma16(w10, b2[(K) * 3 + j]) * GK[j][h];                  \
      }                                                                        \
      {                                                                        \
        const bf16x8 w11 = WFRAG(11, h);                                       \
        const f32x4 m0 = mfma16(w11, b2[0 * 3 + (K)]);                         \
        const f32x4 m1 = mfma16(w11, b2[1 * 3 + (K)]);                         \
        const f32x4 m2 = mfma16(w11, b2[2 * 3 + (K)]);                         \
        const f32x4 tk3 =                                                      \
            (m0 * GK[0][h] + m1 * GK[1][h] + m2 * GK[2][h]) * (1.f / 3.f);     \
        acc2[0][h] += m0 * GK[0][h] - tk3;                                     \
        acc2[4][h] += m1 * GK[1][h] - tk3;                                     \
        acc2[8][h] += m2 * GK[2][h] - tk3;                                     \
        const f32x4 s01 = (m0 * GK[1][h] + m1 * GK[0][h]) * 0.5f;              \
        acc2[1][h] += s01; acc2[3][h] += s01;                                  \
        const f32x4 s02 = (m0 * GK[2][h] + m2 * GK[0][h]) * 0.5f;              \
        acc2[2][h] += s02; acc2[6][h] += s02;                                  \
        const f32x4 s12 = (m1 * GK[2][h] + m2 * GK[1][h]) * 0.5f;              \
        acc2[5][h] += s12; acc2[7][h] += s12;                                  \
      }                                                                        \
    }                                                                          \
  }

  G2ROW_COMPUTE(0, gkA)

  // issue g2 row 2 into the A buffers (rolling)
#pragma unroll
  for (int j = 0; j < 3; ++j) {
    gkA[j][0] = ld4(g2p + (6 + j) * 32);
    gkA[j][1] = ld4(g2p + (6 + j) * 32 + 16);
  }

  G2ROW_COMPUTE(1, gkB)
  G2ROW_COMPUTE(2, gkA)
#undef G2ROW_COMPUTE

  // ---- stores: regular cached float4 pairs; wave covers full 128B lines
  float* o0p = out + (long long)e * 32 + col;
  float* o1p = out + (long long)E * 32 + (long long)e * 96 + col;
  float* o2p = out + (long long)E * 128 + (long long)e * 288 + col;

  *reinterpret_cast<f32x4*>(o0p)      = acc0[0];
  *reinterpret_cast<f32x4*>(o0p + 16) = acc0[1];
#pragma unroll
  for (int s = 0; s < 3; ++s) {
    *reinterpret_cast<f32x4*>(o1p + s * 32)      = acc1[s][0];
    *reinterpret_cast<f32x4*>(o1p + s * 32 + 16) = acc1[s][1];
  }
#pragma unroll
  for (int s = 0; s < 9; ++s) {
    *reinterpret_cast<f32x4*>(o2p + s * 32)      = acc2[s][0];
    *reinterpret_cast<f32x4*>(o2p + s * 32 + 16) = acc2[s][1];
  }
#undef WFRAG
}

// ---------------- fallback (R7, known-passing) if ws too small -------------
__device__ __forceinline__ bf16x8 cvt_frag(f32x4 u, f32x4 v) {
  bf16x8 r;
  r[0] = (__bf16)u[0]; r[1] = (__bf16)u[1]; r[2] = (__bf16)u[2]; r[3] = (__bf16)u[3];
  r[4] = (__bf16)v[0]; r[5] = (__bf16)v[1]; r[6] = (__bf16)v[2]; r[7] = (__bf16)v[3];
  return r;
}

__global__ __launch_bounds__(256, 2)
void leibniz_fused_fb(const float* __restrict__ h0, const float* __restrict__ h1,
                      const float* __restrict__ h2, const float* __restrict__ g0,
                      const float* __restrict__ g1, const float* __restrict__ g2,
                      const float* __restrict__ Wg, const int* __restrict__ src,
                      float* __restrict__ out, int E)
{
  __shared__ bf16x8 wlds[12 * 2 * 4 * 16];
  for (int c = threadIdx.x; c < 12 * 2 * 4 * 16; c += 256) {
    const int gl = c & 15;
    const int qq = (c >> 4) & 3;
    const int hf = (c >> 6) & 1;
    const int p  = c >> 7;
    const float* wp = Wg + (p * 32 + hf * 16 + gl) * 32 + qq * 8;
    bf16x8 f;
#pragma unroll
    for (int j = 0; j < 8; ++j) f[j] = (__bf16)(wp[j] * INV_SQRT_F);
    wlds[c] = f;
  }
  __syncthreads();

  const int lane = threadIdx.x & 63;
  const int wid  = threadIdx.x >> 6;
  const int eidx = lane & 15;
  const int q    = lane >> 4;
  int e0 = (blockIdx.x * 4 + wid) * 16;
  if (e0 > E - 16) e0 = E - 16;

  const int node = src[e0 + eidx];
  const int k0 = q * 8;
  const int e   = e0 + eidx;
  const int col = q * 4;
  const float* g0p = g0 + e * 32 + col;
  const float* g1p = g1 + (long long)e * 96 + col;
  const float* g2p = g2 + (long long)e * 288 + col;

  const float* h0p = h0 + node * 32 + k0;
  const float* h1p = h1 + node * 96 + k0;
  const float* h2p = h2 + (long long)node * 288 + k0;
  f32x4 r0a = ld4(h0p), r0b = ld4(h0p + 4);
  f32x4 r1[6];
#pragma unroll
  for (int s = 0; s < 3; ++s) { r1[2*s] = ld4(h1p + s*32); r1[2*s+1] = ld4(h1p + s*32 + 4); }
  f32x4 r2[18];
#pragma unroll
  for (int s = 0; s < 9; ++s) { r2[2*s] = ld4(h2p + s*32); r2[2*s+1] = ld4(h2p + s*32 + 4); }

  f32x4 gv0[2];
  gv0[0] = ld4(g0p); gv0[1] = ld4(g0p + 16);
  f32x4 gv1[3][2];
#pragma unroll
  for (int s = 0; s < 3; ++s) { gv1[s][0] = ld4(g1p + s*32); gv1[s][1] = ld4(g1p + s*32 + 16); }

  const bf16x8 b0 = cvt_frag(r0a, r0b);
  bf16x8 b1[3];
#pragma unroll
  for (int s = 0; s < 3; ++s) b1[s] = cvt_frag(r1[2*s], r1[2*s+1]);
  bf16x8 b2[9];
#pragma unroll
  for (int s = 0; s < 9; ++s) b2[s] = cvt_frag(r2[2*s], r2[2*s+1]);

  f32x4 gkA[3][2], gkB[3][2];
#pragma unroll
  for (int j = 0; j < 3; ++j) { gkA[j][0] = ld4(g2p + j*32); gkA[j][1] = ld4(g2p + j*32 + 16); }
#pragma unroll
  for (int j = 0; j < 3; ++j) { gkB[j][0] = ld4(g2p + (3+j)*32); gkB[j][1] = ld4(g2p + (3+j)*32 + 16); }

  const f32x4 z4 = {0.f, 0.f, 0.f, 0.f};
  f32x4 acc0[2] = {z4, z4};
  f32x4 acc1[3][2];
  f32x4 acc2[9][2];
#pragma unroll
  for (int s = 0; s < 3; ++s) { acc1[s][0] = z4; acc1[s][1] = z4; }
#pragma unroll
  for (int s = 0; s < 9; ++s) { acc2[s][0] = z4; acc2[s][1] = z4; }

#define WFRAG(P, H) (wlds[(((P) * 2 + (H)) * 4 + q) * 16 + eidx])
#pragma unroll
  for (int h = 0; h < 2; ++h) {
    acc0[h] += mfma16(WFRAG(0, h), b0) * gv0[h];
    const bf16x8 w3 = WFRAG(3, h);
#pragma unroll
    for (int s = 0; s < 3; ++s) acc1[s][h] += mfma16(w3, b1[s]) * gv0[h];
    const bf16x8 w4 = WFRAG(4, h);
#pragma unroll
    for (int s = 0; s < 9; ++s) acc2[s][h] += mfma16(w4, b2[s]) * gv0[h];
  }
#pragma unroll
  for (int h = 0; h < 2; ++h) {
    {
      const f32x4 t = mfma16(WFRAG(1, h), b0);
#pragma unroll
      for (int s = 0; s < 3; ++s) acc1[s][h] += t * gv1[s][h];
    }
    {
      const bf16x8 w5 = WFRAG(5, h);
#pragma unroll
      for (int s = 0; s < 3; ++s) acc0[h] += mfma16(w5, b1[s]) * gv1[s][h];
    }
    {
      const bf16x8 w6 = WFRAG(6, h);
      const f32x4 c0 = mfma16(w6, b1[0]);
      const f32x4 c1 = mfma16(w6, b1[1]);
      const f32x4 c2 = mfma16(w6, b1[2]);
      acc1[0][h] += c1 * gv1[2][h] - c2 * gv1[1][h];
      acc1[1][h] += c2 * gv1[0][h] - c0 * gv1[2][h];
      acc1[2][h] += c0 * gv1[1][h] - c1 * gv1[0][h];
    }
    {
      const bf16x8 w7 = WFRAG(7, h);
      const f32x4 o0 = mfma16(w7, b1[0]);
      const f32x4 o1 = mfma16(w7, b1[1]);
      const f32x4 o2 = mfma16(w7, b1[2]);
      const f32x4 tr3 = (o0 * gv1[0][h] + o1 * gv1[1][h] + o2 * gv1[2][h]) * (1.f / 3.f);
      acc2[0][h] += o0 * gv1[0][h] - tr3;
      acc2[1][h] += o0 * gv1[1][h];
      acc2[2][h] += o0 * gv1[2][h];
      acc2[3][h] += o1 * gv1[0][h];
      acc2[4][h] += o1 * gv1[1][h] - tr3;
      acc2[5][h] += o1 * gv1[2][h];
      acc2[6][h] += o2 * gv1[0][h];
      acc2[7][h] += o2 * gv1[1][h];
      acc2[8][h] += o2 * gv1[2][h] - tr3;
    }
    {
      const bf16x8 w8 = WFRAG(8, h);
#pragma unroll
      for (int i = 0; i < 3; ++i)
#pragma unroll
        for (int j = 0; j < 3; ++j)
          acc1[i][h] += mfma16(w8, b2[i * 3 + j]) * gv1[j][h];
    }
  }

  f32x4 gkC[3][2];
#pragma unroll
  for (int j = 0; j < 3; ++j) { gkC[j][0] = ld4(g2p + (6+j)*32); gkC[j][1] = ld4(g2p + (6+j)*32 + 16); }

  f32x4 t2[2];
  t2[0] = mfma16(WFRAG(2, 0), b0);
  t2[1] = mfma16(WFRAG(2, 1), b0);

#define G2ROW_COMPUTE(K, GK)                                                   \
  {                                                                            \
    _Pragma("unroll")                                                          \
    for (int h = 0; h < 2; ++h) {                                              \
      _Pragma("unroll")                                                        \
      for (int j = 0; j < 3; ++j) acc2[(K) * 3 + j][h] += t2[h] * GK[j][h];    \
      {                                                                        \
        const f32x4 vk = mfma16(WFRAG(9, h), b1[(K)]);                         \
        _Pragma("unroll")                                                      \
        for (int j = 0; j < 3; ++j) acc1[j][h] += vk * GK[j][h];               \
      }                                                                        \
      {                                                                        \
        const bf16x8 w10 = WFRAG(10, h);                                       \
        _Pragma("unroll")                                                      \
        for (int j = 0; j < 3; ++j)                                            \
          acc0[h] += mfma16(w10, b2[(K) * 3 + j]) * GK[j][h];                  \
      }                                                                        \
      {                                                                        \
        const bf16x8 w11 = WFRAG(11, h);                                       \
        const f32x4 m0 = mfma16(w11, b2[0 * 3 + (K)]);                         \
        const f32x4 m1 = mfma16(w11, b2[1 * 3 + (K)]);                         \
        const f32x4 m2 = mfma16(w11, b2[2 * 3 + (K)]);                         \
        const f32x4 tk3 =                                                      \
            (m0 * GK[0][h] + m1 * GK[1][h] + m2 * GK[2][h]) * (1.f / 3.f);     \
        acc2[0][h] += m0 * GK[0][h] - tk3;                                     \
        acc2[4][h] += m1 * GK[1][h] - tk3;                                     \
        acc2[8][h] += m2 * GK[2][h] - tk3;                                     \
        const f32x4 s01 = (m0 * GK[1][h] + m1 * GK[0][h]) * 0.5f;              \
        acc2[1][h] += s01; acc2[3][h] += s01;                                  \
        const f32x4 s02 = (m0 * GK[2][h] + m2 * GK[0][h]) * 0.5f;              \
        acc2[2][h] += s02; acc2[6][h] += s02;                                  \
        const f32x4 s12 = (m1 * GK[2][h] + m2 * GK[1][h]) * 0.5f;              \
        acc2[5][h] += s12; acc2[7][h] += s12;                                  \
      }                                                                        \
    }                                                                          \
  }

  G2ROW_COMPUTE(0, gkA)
  G2ROW_COMPUTE(1, gkB)
  G2ROW_COMPUTE(2, gkC)
#undef G2ROW_COMPUTE

  float* o0p = out + (long long)e * 32 + col;
  float* o1p = out + (long long)E * 32 + (long long)e * 96 + col;
  float* o2p = out + (long long)E * 128 + (long long)e * 288 + col;
  *reinterpret_cast<f32x4*>(o0p)      = acc0[0];
  *reinterpret_cast<f32x4*>(o0p + 16) = acc0[1];
#pragma unroll
  for (int s = 0; s < 3; ++s) {
    *reinterpret_cast<f32x4*>(o1p + s * 32)      = acc1[s][0];
    *reinterpret_cast<f32x4*>(o1p + s * 32 + 16) = acc1[s][1];
  }
#pragma unroll
  for (int s = 0; s < 9; ++s) {
    *reinterpret_cast<f32x4*>(o2p + s * 32)      = acc2[s][0];
    *reinterpret_cast<f32x4*>(o2p + s * 32 + 16) = acc2[s][1];
  }
#undef WFRAG
}

extern "C" void kernel_launch(void* const* d_in, const int* in_sizes, int n_in,
                              void* d_out, int out_size, void* d_ws, size_t ws_size,
                              hipStream_t stream) {
  const float* h0 = (const float*)d_in[0];
  const float* h1 = (const float*)d_in[1];
  const float* h2 = (const float*)d_in[2];
  const float* g0 = (const float*)d_in[3];
  const float* g1 = (const float*)d_in[4];
  const float* g2 = (const float*)d_in[5];
  const float* Wg = (const float*)d_in[6];
  const int* src = (const int*)d_in[7];  // harness passes integer inputs as int32
  const int E = in_sizes[7];
  const int n0 = in_sizes[0], n1 = in_sizes[1], n2 = in_sizes[2];
  const size_t need = 24576 + (size_t)(n0 + n1 + n2) * 2;
  const int blocks = (E + 63) / 64;  // 4 waves x 16 edges

  if (ws_size >= need) {
    __bf16* ws = (__bf16*)d_ws;
    leibniz_prepass<<<2048, 256, 0, stream>>>(h0, h1, h2, Wg, ws, n0, n1, n2);
    leibniz_fused_b<<<blocks, 256, 0, stream>>>(ws, g0, g1, g2, src,
                                                (float*)d_out, E, n0, n1);
  } else {
    leibniz_fused_fb<<<blocks, 256, 0, stream>>>(h0, h1, h2, g0, g1, g2, Wg, src,
                                                 (float*)d_out, E);
  }
}

// Round 9
// 141.251 us; speedup vs baseline: 1.3314x; 1.3314x over previous
//
#include <hip/hip_runtime.h>
#include <stdint.h>

typedef float f32x4 __attribute__((ext_vector_type(4)));
typedef __bf16 bf16x8 __attribute__((ext_vector_type(8)));
typedef __bf16 bf16x4 __attribute__((ext_vector_type(4)));

constexpr float INV_SQRT_F = 0.17677669529663687f;  // 32^-0.5

__device__ __forceinline__ f32x4 mfma16(bf16x8 a, bf16x8 b) {
  const f32x4 z = {0.f, 0.f, 0.f, 0.f};
  return __builtin_amdgcn_mfma_f32_16x16x32_bf16(a, b, z, 0, 0, 0);
}
__device__ __forceinline__ f32x4 ld4(const float* p) {
  return *reinterpret_cast<const f32x4*>(p);
}
__device__ __forceinline__ bf16x8 ldb8(const __bf16* __restrict__ p) {
  return *reinterpret_cast<const bf16x8*>(p);
}
// async global->LDS DMA, 16B per lane. gp: PER-LANE global address;
// lp: WAVE-UNIFORM LDS base (hardware adds lane*16).
__device__ __forceinline__ void stage16(const float* gp, float* lp) {
  __builtin_amdgcn_global_load_lds(
      (const __attribute__((address_space(1))) void*)gp,
      (__attribute__((address_space(3))) void*)lp, 16, 0, 0);
}

// ---------------- pre-pass: h -> bf16, W -> scaled frag-layout bf16 (R8) ---
__global__ __launch_bounds__(256)
void leibniz_prepass(const float* __restrict__ h0, const float* __restrict__ h1,
                     const float* __restrict__ h2, const float* __restrict__ Wg,
                     __bf16* __restrict__ ws, int n0, int n1, int n2)
{
  if (blockIdx.x == 0) {
    bf16x8* wsW = reinterpret_cast<bf16x8*>(ws);
    for (int c = threadIdx.x; c < 12 * 2 * 4 * 16; c += 256) {
      const int gl = c & 15;
      const int qq = (c >> 4) & 3;
      const int hf = (c >> 6) & 1;
      const int p  = c >> 7;
      const float* wp = Wg + (p * 32 + hf * 16 + gl) * 32 + qq * 8;
      bf16x8 f;
#pragma unroll
      for (int j = 0; j < 8; ++j) f[j] = (__bf16)(wp[j] * INV_SQRT_F);
      wsW[c] = f;
    }
  }
  __bf16* hb0 = ws + 12288;
  __bf16* hb1 = hb0 + n0;
  __bf16* hb2 = hb1 + n1;
  const int q0 = n0 >> 2, q1 = n1 >> 2, q2 = n2 >> 2;
  const int total = q0 + q1 + q2;
  for (int i = blockIdx.x * 256 + threadIdx.x; i < total; i += gridDim.x * 256) {
    const float* sp;
    __bf16* dp;
    if (i < q0)           { sp = h0 + 4 * i;              dp = hb0 + 4 * i; }
    else if (i < q0 + q1) { int j = i - q0;      sp = h1 + 4 * j; dp = hb1 + 4 * j; }
    else                  { int j = i - q0 - q1; sp = h2 + 4 * j; dp = hb2 + 4 * j; }
    const f32x4 v = *reinterpret_cast<const f32x4*>(sp);
    bf16x4 o;
    o[0] = (__bf16)v[0]; o[1] = (__bf16)v[1]; o[2] = (__bf16)v[2]; o[3] = (__bf16)v[3];
    *reinterpret_cast<bf16x4*>(dp) = o;
  }
}

// ---------------- main: per-wave LDS-DMA double-buffered tile pipeline -----
// Block = 1 wave. Wave grid-strides over 16-edge tiles. Tile t's full g
// (g0 2KB + g1 6KB + g2 18KB = 26.6KB) is staged via global_load_lds into
// buf[cur^1] WHILE tile t-1 computes -> 208 lines in flight per wave during
// the whole compute phase (fixes R5's ~5). Staging SOURCE addresses are
// pre-permuted so LDS chunk (u, lane) holds g[e0+(lane&15)][row u>>1]
// [half u&1][(lane>>4)*16B] -> consumer ds_read_b128 at lane*16 linear,
// conflict-free. One vmcnt(0) per ~7K-cycle tile; all prefetches (g-DMA,
// h-frags, src) are consumed only after the NEXT iteration's vmcnt(0), so
// vmcnt in-order retire never forces a mid-tile drain. W in registers
// (MFMA-only -> AGPR-eligible); h from bf16 ws (R8 prepass).
__global__ __launch_bounds__(64)
void leibniz_pipe(const __bf16* __restrict__ wsAll,
                  const float* __restrict__ g0, const float* __restrict__ g1,
                  const float* __restrict__ g2, const int* __restrict__ src,
                  float* __restrict__ out, int E, int n0, int n1)
{
  __shared__ __align__(16) float sbuf[2 * 6656];  // 53,248 B

  const int lane = threadIdx.x;        // 64 threads = one wave
  const int eidx = lane & 15;          // edge within tile
  const int q    = lane >> 4;          // feature quad

  // W fragments -> registers: w[p*2+h], ws chunk index ph*64 + q*16 + eidx
  const bf16x8* wsW = reinterpret_cast<const bf16x8*>(wsAll);
  bf16x8 w[24];
#pragma unroll
  for (int c = 0; c < 24; ++c) w[c] = wsW[c * 64 + q * 16 + eidx];

  const __bf16* hb0 = wsAll + 12288;
  const __bf16* hb1 = hb0 + n0;
  const __bf16* hb2 = hb1 + n1;

  const int NT  = (E + 15) >> 4;
  const int NBg = gridDim.x;
  const long long o1base = (long long)E * 32;
  const long long o2base = (long long)E * 128;

#define EBASE(T) ((long long)(T) * 16 > (long long)E - 16 ? (long long)E - 16 \
                                                          : (long long)(T) * 16)

#define STAGE(TILE, NB_) do {                                                  \
  const long long eb_ = EBASE(TILE);                                           \
  float* lb_ = sbuf + (NB_) * 6656;                                            \
  const float* s0_ = g0 + (eb_ + eidx) * 32 + q * 4;                           \
  stage16(s0_,      lb_);                                                      \
  stage16(s0_ + 16, lb_ + 256);                                                \
  const float* s1_ = g1 + (eb_ + eidx) * 96 + q * 4;                           \
  _Pragma("unroll")                                                            \
  for (int u = 0; u < 6; ++u)                                                  \
    stage16(s1_ + (u >> 1) * 32 + (u & 1) * 16, lb_ + 512 + u * 256);          \
  const float* s2_ = g2 + (eb_ + eidx) * 288 + q * 4;                          \
  _Pragma("unroll")                                                            \
  for (int u = 0; u < 18; ++u)                                                 \
    stage16(s2_ + (u >> 1) * 32 + (u & 1) * 16, lb_ + 2048 + u * 256);         \
} while (0)

#define LOAD_H(NODE, B0, B1, B2) do {                                          \
  const __bf16* p0_ = hb0 + (long long)(NODE) * 32 + q * 8;                    \
  B0 = ldb8(p0_);                                                              \
  const __bf16* p1_ = hb1 + (long long)(NODE) * 96 + q * 8;                    \
  _Pragma("unroll") for (int s = 0; s < 3; ++s) B1[s] = ldb8(p1_ + s * 32);    \
  const __bf16* p2_ = hb2 + (long long)(NODE) * 288 + q * 8;                   \
  _Pragma("unroll") for (int s = 0; s < 9; ++s) B2[s] = ldb8(p2_ + s * 32);    \
} while (0)

#define WFRAG(P, H) (w[(P) * 2 + (H)])

#define COMPUTE_STORE(TILE, CUR, B0, B1, B2) do {                              \
  const long long e_ = EBASE(TILE) + eidx;                                     \
  const float* lb = sbuf + (CUR) * 6656 + lane * 4;                            \
  const f32x4 z4 = {0.f, 0.f, 0.f, 0.f};                                       \
  f32x4 acc0[2] = {z4, z4};                                                    \
  f32x4 acc1[3][2];                                                            \
  f32x4 acc2[9][2];                                                            \
  _Pragma("unroll")                                                            \
  for (int s = 0; s < 3; ++s) { acc1[s][0] = z4; acc1[s][1] = z4; }            \
  _Pragma("unroll")                                                            \
  for (int s = 0; s < 9; ++s) { acc2[s][0] = z4; acc2[s][1] = z4; }            \
  /* g0 phase: paths 0,3,4 (prod) */                                           \
  {                                                                            \
    f32x4 gv0[2];                                                              \
    gv0[0] = ld4(lb);                                                          \
    gv0[1] = ld4(lb + 256);                                                    \
    _Pragma("unroll")                                                          \
    for (int h = 0; h < 2; ++h) {                                              \
      acc0[h] += mfma16(WFRAG(0, h), B0) * gv0[h];                             \
      const bf16x8 w3 = WFRAG(3, h);                                           \
      _Pragma("unroll")                                                        \
      for (int s = 0; s < 3; ++s) acc1[s][h] += mfma16(w3, B1[s]) * gv0[h];    \
      const bf16x8 w4 = WFRAG(4, h);                                           \
      _Pragma("unroll")                                                        \
      for (int s = 0; s < 9; ++s) acc2[s][h] += mfma16(w4, B2[s]) * gv0[h];    \
    }                                                                          \
  }                                                                            \
  /* g1 phase: paths 1,5,6,7,8 */                                              \
  {                                                                            \
    f32x4 gv1[3][2];                                                           \
    _Pragma("unroll")                                                          \
    for (int s = 0; s < 3; ++s) {                                              \
      gv1[s][0] = ld4(lb + 512 + (s * 2) * 256);                               \
      gv1[s][1] = ld4(lb + 512 + (s * 2 + 1) * 256);                           \
    }                                                                          \
    _Pragma("unroll")                                                          \
    for (int h = 0; h < 2; ++h) {                                              \
      {                                                                        \
        const f32x4 t = mfma16(WFRAG(1, h), B0);                               \
        _Pragma("unroll")                                                      \
        for (int s = 0; s < 3; ++s) acc1[s][h] += t * gv1[s][h];               \
      }                                                                        \
      {                                                                        \
        const bf16x8 w5 = WFRAG(5, h);                                         \
        _Pragma("unroll")                                                      \
        for (int s = 0; s < 3; ++s) acc0[h] += mfma16(w5, B1[s]) * gv1[s][h];  \
      }                                                                        \
      {                                                                        \
        const bf16x8 w6 = WFRAG(6, h);                                         \
        const f32x4 c0 = mfma16(w6, B1[0]);                                    \
        const f32x4 c1 = mfma16(w6, B1[1]);                                    \
        const f32x4 c2 = mfma16(w6, B1[2]);                                    \
        acc1[0][h] += c1 * gv1[2][h] - c2 * gv1[1][h];                         \
        acc1[1][h] += c2 * gv1[0][h] - c0 * gv1[2][h];                         \
        acc1[2][h] += c0 * gv1[1][h] - c1 * gv1[0][h];                         \
      }                                                                        \
      {                                                                        \
        const bf16x8 w7 = WFRAG(7, h);                                         \
        const f32x4 o0 = mfma16(w7, B1[0]);                                    \
        const f32x4 o1 = mfma16(w7, B1[1]);                                    \
        const f32x4 o2 = mfma16(w7, B1[2]);                                    \
        const f32x4 tr3 =                                                      \
            (o0 * gv1[0][h] + o1 * gv1[1][h] + o2 * gv1[2][h]) * (1.f / 3.f);  \
        acc2[0][h] += o0 * gv1[0][h] - tr3;                                    \
        acc2[1][h] += o0 * gv1[1][h];                                          \
        acc2[2][h] += o0 * gv1[2][h];                                          \
        acc2[3][h] += o1 * gv1[0][h];                                          \
        acc2[4][h] += o1 * gv1[1][h] - tr3;                                    \
        acc2[5][h] += o1 * gv1[2][h];                                          \
        acc2[6][h] += o2 * gv1[0][h];                                          \
        acc2[7][h] += o2 * gv1[1][h];                                          \
        acc2[8][h] += o2 * gv1[2][h] - tr3;                                    \
      }                                                                        \
      {                                                                        \
        const bf16x8 w8 = WFRAG(8, h);                                         \
        _Pragma("unroll")                                                      \
        for (int i = 0; i < 3; ++i)                                            \
          _Pragma("unroll")                                                    \
          for (int j = 0; j < 3; ++j)                                          \
            acc1[i][h] += mfma16(w8, B2[i * 3 + j]) * gv1[j][h];               \
      }                                                                        \
    }                                                                          \
  }                                                                            \
  /* g2 phase: paths 2,9,10,11; one 3x2-vector row live per k */               \
  {                                                                            \
    f32x4 t2[2];                                                               \
    t2[0] = mfma16(WFRAG(2, 0), B0);                                           \
    t2[1] = mfma16(WFRAG(2, 1), B0);                                           \
    _Pragma("unroll")                                                          \
    for (int k = 0; k < 3; ++k) {                                              \
      f32x4 gk[3][2];                                                          \
      _Pragma("unroll")                                                        \
      for (int j = 0; j < 3; ++j) {                                            \
        gk[j][0] = ld4(lb + 2048 + ((k * 3 + j) * 2) * 256);                   \
        gk[j][1] = ld4(lb + 2048 + ((k * 3 + j) * 2 + 1) * 256);               \
      }                                                                        \
      _Pragma("unroll")                                                        \
      for (int h = 0; h < 2; ++h) {                                            \
        _Pragma("unroll")                                                      \
        for (int j = 0; j < 3; ++j) acc2[k * 3 + j][h] += t2[h] * gk[j][h];    \
        {                                                                      \
          const f32x4 vk = mfma16(WFRAG(9, h), B1[k]);                         \
          _Pragma("unroll")                                                    \
          for (int j = 0; j < 3; ++j) acc1[j][h] += vk * gk[j][h];             \
        }                                                                      \
        {                                                                      \
          const bf16x8 w10 = WFRAG(10, h);                                     \
          _Pragma("unroll")                                                    \
          for (int j = 0; j < 3; ++j)                                          \
            acc0[h] += mfma16(w10, B2[k * 3 + j]) * gk[j][h];                  \
        }                                                                      \
        {                                                                      \
          const bf16x8 w11 = WFRAG(11, h);                                     \
          const f32x4 m0 = mfma16(w11, B2[0 * 3 + k]);                         \
          const f32x4 m1 = mfma16(w11, B2[1 * 3 + k]);                         \
          const f32x4 m2 = mfma16(w11, B2[2 * 3 + k]);                         \
          const f32x4 tk3 =                                                    \
              (m0 * gk[0][h] + m1 * gk[1][h] + m2 * gk[2][h]) * (1.f / 3.f);   \
          acc2[0][h] += m0 * gk[0][h] - tk3;                                   \
          acc2[4][h] += m1 * gk[1][h] - tk3;                                   \
          acc2[8][h] += m2 * gk[2][h] - tk3;                                   \
          const f32x4 s01 = (m0 * gk[1][h] + m1 * gk[0][h]) * 0.5f;            \
          acc2[1][h] += s01; acc2[3][h] += s01;                                \
          const f32x4 s02 = (m0 * gk[2][h] + m2 * gk[0][h]) * 0.5f;            \
          acc2[2][h] += s02; acc2[6][h] += s02;                                \
          const f32x4 s12 = (m1 * gk[2][h] + m2 * gk[1][h]) * 0.5f;            \
          acc2[5][h] += s12; acc2[7][h] += s12;                                \
        }                                                                      \
      }                                                                        \
    }                                                                          \
  }                                                                            \
  /* stores: float4 pairs; wave covers full 128B lines */                      \
  {                                                                            \
    const int col = q * 4;                                                     \
    float* o0p = out + e_ * 32 + col;                                          \
    float* o1p = out + o1base + e_ * 96 + col;                                 \
    float* o2p = out + o2base + e_ * 288 + col;                                \
    *reinterpret_cast<f32x4*>(o0p)      = acc0[0];                             \
    *reinterpret_cast<f32x4*>(o0p + 16) = acc0[1];                             \
    _Pragma("unroll")                                                          \
    for (int s = 0; s < 3; ++s) {                                              \
      *reinterpret_cast<f32x4*>(o1p + s * 32)      = acc1[s][0];               \
      *reinterpret_cast<f32x4*>(o1p + s * 32 + 16) = acc1[s][1];               \
    }                                                                          \
    _Pragma("unroll")                                                          \
    for (int s = 0; s < 9; ++s) {                                              \
      *reinterpret_cast<f32x4*>(o2p + s * 32)      = acc2[s][0];               \
      *reinterpret_cast<f32x4*>(o2p + s * 32 + 16) = acc2[s][1];               \
    }                                                                          \
  }                                                                            \
} while (0)

  // ---- prologue
  int tile = blockIdx.x;
  if (tile >= NT) return;

  int ncur = src[EBASE(tile) + eidx];  // src(t0): plain load, waited below
  STAGE(tile, 0);                      // g(t0) -> buf0
  bf16x8 bA0, bA1[3], bA2[9];
  bf16x8 bB0, bB1[3], bB2[9];
  LOAD_H(ncur, bA0, bA1, bA2);         // h(t0) (consumed after iter-0 vmcnt)
  int nnext = 0;
  {
    const int t1 = tile + NBg;
    if (t1 < NT) nnext = src[EBASE(t1) + eidx];  // src(t1)
  }
  int cur = 0;

  // Per iteration: drain (buf[cur], h(t), src(t+1) all ready) -> issue
  // DMA-stage(t+1)+h(t+1)+src(t+2) -> compute+store t. Prefetches stay in
  // flight across the whole compute; consumed only after next drain.
#define ITER(BC0, BC1, BC2, BN0, BN1, BN2)                                     \
  {                                                                            \
    asm volatile("s_waitcnt vmcnt(0)" ::: "memory");                           \
    const int tn_ = tile + NBg;                                                \
    const bool hn_ = tn_ < NT;                                                 \
    if (hn_) {                                                                 \
      STAGE(tn_, cur ^ 1);                                                     \
      LOAD_H(nnext, BN0, BN1, BN2);                                            \
      const int t2_ = tile + 2 * NBg;                                          \
      if (t2_ < NT) nnext = src[EBASE(t2_) + eidx];                            \
    }                                                                          \
    COMPUTE_STORE(tile, cur, BC0, BC1, BC2);                                   \
    if (!hn_) break;                                                           \
    tile = tn_;                                                                \
    cur ^= 1;                                                                  \
  }

  for (;;) {
    ITER(bA0, bA1, bA2, bB0, bB1, bB2)
    ITER(bB0, bB1, bB2, bA0, bA1, bA2)
  }

#undef ITER
#undef COMPUTE_STORE
#undef WFRAG
#undef LOAD_H
#undef STAGE
#undef EBASE
}

extern "C" void kernel_launch(void* const* d_in, const int* in_sizes, int n_in,
                              void* d_out, int out_size, void* d_ws, size_t ws_size,
                              hipStream_t stream) {
  const float* h0 = (const float*)d_in[0];
  const float* h1 = (const float*)d_in[1];
  const float* h2 = (const float*)d_in[2];
  const float* g0 = (const float*)d_in[3];
  const float* g1 = (const float*)d_in[4];
  const float* g2 = (const float*)d_in[5];
  const float* Wg = (const float*)d_in[6];
  const int* src = (const int*)d_in[7];  // harness passes integer inputs as int32
  const int E = in_sizes[7];
  const int n0 = in_sizes[0], n1 = in_sizes[1], n2 = in_sizes[2];
  __bf16* ws = (__bf16*)d_ws;  // 24KB W frags + bf16 h (ws_size verified ample in R8)

  leibniz_prepass<<<2048, 256, 0, stream>>>(h0, h1, h2, Wg, ws, n0, n1, n2);

  const int NT = (E + 15) / 16;
  int blocks = 768;                    // 256 CU x 3 resident waves (LDS-limited)
  if (blocks > NT) blocks = NT;
  leibniz_pipe<<<blocks, 64, 0, stream>>>(ws, g0, g1, g2, src,
                                          (float*)d_out, E, n0, n1);
}